// Round 4
// baseline (643.031 us; speedup 1.0000x reference)
//
#include <hip/hip_runtime.h>
#include <hip/hip_cooperative_groups.h>

namespace cg = cooperative_groups;

// ---------------------------------------------------------------------------
// R4: cooperative mega-kernel, 512 blocks (2/CU guaranteed co-resident),
// with runtime fallback to the R2 multi-kernel pipeline if the cooperative
// launch is rejected (return code checked; deterministic every call).
// Phases: A activity partials -> B top-2 -> C transposes -> D GEMM1 -> E GEMM2
// ---------------------------------------------------------------------------

typedef __bf16 bf16x8_t __attribute__((ext_vector_type(8)));
typedef float  f32x4_t  __attribute__((ext_vector_type(4)));

__device__ inline unsigned short f2bf(float f) {
    __bf16 b = (__bf16)f;
    return __builtin_bit_cast(unsigned short, b);
}

// async stage of 8 rows (wave-uniform row0) from bf16 global, 16 B/lane,
// XOR-swizzled granules: LDS slot gs holds global granule gs ^ (row & 7)
__device__ inline void stage_glds(const unsigned short* gtile, int stride, int row0,
                                  unsigned short* lds, int lane) {
    const int r8 = lane >> 3;
    const int gg = (lane & 7) ^ r8;
    const unsigned short* gp = gtile + (size_t)(row0 + r8) * stride + gg * 8;
    unsigned short* lp = lds + row0 * 64;
    __builtin_amdgcn_global_load_lds((const __attribute__((address_space(1))) void*)gp,
                                     (__attribute__((address_space(3))) void*)lp,
                                     16, 0, 0);
}

__device__ inline bf16x8_t ldsfrag(const unsigned short* Ls, int row, int kb) {
    return *(const bf16x8_t*)(Ls + row * 64 + (((kb >> 3) ^ (row & 7)) * 8));
}

// ---------------- GEMM1 tile body (64x64, fused gather) --------------------
__device__ inline void gemm1_tile(const float* __restrict__ x, const unsigned short* __restrict__ wct,
                                  const float* __restrict__ bc, unsigned short* __restrict__ h,
                                  int z, int idxz, int m0, int n0,
                                  unsigned short* As, unsigned short* Bs,
                                  int tid, int wave, int lane) {
    const int wm = (wave >> 1) * 32;
    const int wn = (wave & 1) * 32;
    const int rl = lane & 15;
    const int quad = lane >> 4;
    const float* xtile = x + (size_t)m0 * 4096 + idxz * 512;
    const unsigned short* bttile = wct + (size_t)z * 262144 + (size_t)n0 * 512;

    f32x4_t acc[2][2] = {};
    const int ar = tid >> 2;
    const int aq = tid & 3;

    for (int k0 = 0; k0 < 512; k0 += 64) {
        #pragma unroll
        for (int s = wave; s < 8; s += 4)
            stage_glds(bttile + k0, 512, s * 8, Bs, lane);
        const float* gr = xtile + (size_t)ar * 4096 + k0;
        #pragma unroll
        for (int j = 0; j < 2; ++j) {
            int gg = aq * 2 + j;
            float4 a = *(const float4*)(gr + gg * 8);
            float4 c = *(const float4*)(gr + gg * 8 + 4);
            bf16x8_t v;
            v[0] = (__bf16)a.x; v[1] = (__bf16)a.y; v[2] = (__bf16)a.z; v[3] = (__bf16)a.w;
            v[4] = (__bf16)c.x; v[5] = (__bf16)c.y; v[6] = (__bf16)c.z; v[7] = (__bf16)c.w;
            *(bf16x8_t*)(As + ar * 64 + ((gg ^ (ar & 7)) * 8)) = v;
        }
        __syncthreads();
        #pragma unroll
        for (int kq = 0; kq < 2; ++kq) {
            const int kb = kq * 32 + quad * 8;
            bf16x8_t af[2], bfr[2];
            #pragma unroll
            for (int i = 0; i < 2; ++i) {
                af[i]  = ldsfrag(As, wm + i * 16 + rl, kb);
                bfr[i] = ldsfrag(Bs, wn + i * 16 + rl, kb);
            }
            #pragma unroll
            for (int mi = 0; mi < 2; ++mi)
                #pragma unroll
                for (int ni = 0; ni < 2; ++ni)
                    acc[mi][ni] = __builtin_amdgcn_mfma_f32_16x16x32_bf16(af[mi], bfr[ni], acc[mi][ni], 0, 0, 0);
        }
        __syncthreads();
    }

    const int row_l = quad * 4;
    const float* bias = bc + (size_t)idxz * 512;
    #pragma unroll
    for (int ni = 0; ni < 2; ++ni) {
        int col = n0 + wn + ni * 16 + rl;
        float bv = bias[col];
        #pragma unroll
        for (int mi = 0; mi < 2; ++mi) {
            #pragma unroll
            for (int j = 0; j < 4; ++j) {
                int row = m0 + wm + mi * 16 + row_l + j;
                h[(size_t)row * 1024 + z * 512 + col] = f2bf(acc[mi][ni][j] + bv);
            }
        }
    }
}

// ---------------- GEMM2 tile body (128x128) --------------------------------
__device__ inline void gemm2_tile(const unsigned short* __restrict__ h, const unsigned short* __restrict__ wft,
                                  const float* __restrict__ bfin, float* __restrict__ out,
                                  int m0, int n0, unsigned short* As, unsigned short* Bs,
                                  int wave, int lane) {
    const int wm = (wave >> 1) * 64;
    const int wn = (wave & 1) * 64;
    const int rl = lane & 15;
    const int quad = lane >> 4;
    const unsigned short* Atile = h + (size_t)m0 * 1024;
    const unsigned short* Btile = wft + (size_t)n0 * 1024;

    f32x4_t acc[4][4] = {};

    for (int k0 = 0; k0 < 1024; k0 += 64) {
        #pragma unroll
        for (int s = wave; s < 32; s += 4) {
            if (s < 16) stage_glds(Atile + k0, 1024, s * 8, As, lane);
            else        stage_glds(Btile + k0, 1024, (s - 16) * 8, Bs, lane);
        }
        __syncthreads();
        #pragma unroll
        for (int kq = 0; kq < 2; ++kq) {
            const int kb = kq * 32 + quad * 8;
            bf16x8_t af[4], bfr[4];
            #pragma unroll
            for (int i = 0; i < 4; ++i) {
                af[i]  = ldsfrag(As, wm + i * 16 + rl, kb);
                bfr[i] = ldsfrag(Bs, wn + i * 16 + rl, kb);
            }
            #pragma unroll
            for (int mi = 0; mi < 4; ++mi)
                #pragma unroll
                for (int ni = 0; ni < 4; ++ni)
                    acc[mi][ni] = __builtin_amdgcn_mfma_f32_16x16x32_bf16(af[mi], bfr[ni], acc[mi][ni], 0, 0, 0);
        }
        __syncthreads();
    }

    const int row_l = quad * 4;
    float bv[4];
    #pragma unroll
    for (int ni = 0; ni < 4; ++ni) bv[ni] = bfin[n0 + wn + ni * 16 + rl];
    #pragma unroll
    for (int mi = 0; mi < 4; ++mi) {
        #pragma unroll
        for (int ni = 0; ni < 4; ++ni) {
            int col = n0 + wn + ni * 16 + rl;
            #pragma unroll
            for (int j = 0; j < 4; ++j) {
                int row = m0 + wm + mi * 16 + row_l + j;
                out[(size_t)row * 4096 + col] = acc[mi][ni][j] + bv[ni];
            }
        }
    }
}

// ======================= cooperative mega-kernel ===========================
__global__ __launch_bounds__(256, 2)
void mega_kernel(const float* __restrict__ x, const float* __restrict__ Wc,
                 const float* __restrict__ bc, const float* __restrict__ Wf,
                 const float* __restrict__ bfin, float* __restrict__ out,
                 float* __restrict__ part, int* __restrict__ idxg,
                 unsigned short* __restrict__ h, unsigned short* __restrict__ wct,
                 unsigned short* __restrict__ wft) {
    cg::grid_group grid = cg::this_grid();
    __shared__ __align__(16) unsigned char lds_raw[32 * 1024];

    const int b = blockIdx.x;          // 0..511
    const int tid = threadIdx.x;
    const int wave = tid >> 6;
    const int lane = tid & 63;

    // ---------------- phase A: activity partials (512 jobs, 64 rows each) ---
    {
        const int chunk = b & 7;
        const int rg = b >> 3;                 // 0..63
        const int colf4 = tid & 127;
        const int rsub = tid >> 7;
        const float4* base = (const float4*)x + (size_t)chunk * 128 + colf4;
        float s = 0.f;
        #pragma unroll 4
        for (int i = 0; i < 32; ++i) {
            int row = rg * 64 + i * 2 + rsub;
            float4 v = base[(size_t)row * 1024];
            s += fabsf(v.x) + fabsf(v.y) + fabsf(v.z) + fabsf(v.w);
        }
        #pragma unroll
        for (int off = 32; off > 0; off >>= 1) s += __shfl_down(s, off, 64);
        float* wsum = (float*)lds_raw;
        if (lane == 0) wsum[wave] = s;
        __syncthreads();
        if (tid == 0) part[chunk * 64 + rg] = wsum[0] + wsum[1] + wsum[2] + wsum[3];
    }
    __threadfence();
    grid.sync();

    // ---------------- phase B: reduce + top-2 (block 0, 256 threads) -------
    if (b == 0) {
        float* red = (float*)lds_raw;          // 256 floats
        float* act8 = (float*)(lds_raw + 1024);
        const int c = tid >> 5, j = tid & 31;
        red[tid] = part[c * 64 + j] + part[c * 64 + j + 32];
        __syncthreads();
        if (tid < 8) {
            float a = 0.f;
            for (int k = 0; k < 32; ++k) a += red[tid * 32 + k];
            act8[tid] = a;
        }
        __syncthreads();
        if (tid == 0) {
            float v0 = -1e30f, v1 = -1e30f; int b0 = 0, b1 = 0;
            for (int i = 0; i < 8; ++i) {
                float v = act8[i];
                if (v > v0) { v1 = v0; b1 = b0; v0 = v; b0 = i; }
                else if (v > v1) { v1 = v; b1 = i; }
            }
            idxg[0] = b0; idxg[1] = b1;
        }
    }
    __threadfence();
    grid.sync();

    const int sel0 = ((volatile int*)idxg)[0];
    const int sel1 = ((volatile int*)idxg)[1];

    // ---------------- phase C: transposes (4608 jobs, stride 512) ----------
    {
        float (*tile)[33] = (float (*)[33])lds_raw;
        const int tx = tid & 31, ty = tid >> 5;
        for (int j = b; j < 4608; j += 512) {
            const float* src; unsigned short* dst; int R, C, cb, rb;
            if (j < 4096) {        // Wf^T: 1024x4096 -> 4096x1024
                src = Wf; dst = wft; R = 1024; C = 4096;
                cb = (j & 127) * 32; rb = (j >> 7) * 32;
            } else {               // Wc[sel]^T
                int jj = j - 4096;
                int z = jj >> 8; int t = jj & 255;
                src = Wc + (size_t)(z ? sel1 : sel0) * 262144;
                dst = wct + (size_t)z * 262144;
                R = 512; C = 512;
                cb = (t & 15) * 32; rb = (t >> 4) * 32;
            }
            __syncthreads();
            #pragma unroll
            for (int i = 0; i < 4; ++i)
                tile[ty + i * 8][tx] = src[(size_t)(rb + ty + i * 8) * C + cb + tx];
            __syncthreads();
            #pragma unroll
            for (int i = 0; i < 4; ++i)
                dst[(size_t)(cb + ty + i * 8) * R + rb + tx] = f2bf(tile[tx][ty + i * 8]);
        }
    }
    __threadfence();
    grid.sync();

    // ---------------- phase D: GEMM1, 1024 tiles, 2 per block --------------
    {
        unsigned short* As = (unsigned short*)lds_raw;
        unsigned short* Bs = (unsigned short*)(lds_raw + 8192);
        #pragma unroll
        for (int t = b; t < 1024; t += 512) {
            const int z = t >> 9;
            const int tt = t & 511;
            gemm1_tile(x, wct, bc, h, z, z ? sel1 : sel0,
                       (tt >> 3) * 64, (tt & 7) * 64, As, Bs, tid, wave, lane);
        }
    }
    __threadfence();
    grid.sync();

    // ---------------- phase E: GEMM2, 1024 tiles, 2 per block --------------
    {
        unsigned short* As = (unsigned short*)lds_raw;
        unsigned short* Bs = (unsigned short*)(lds_raw + 16384);
        #pragma unroll
        for (int t = b; t < 1024; t += 512)
            gemm2_tile(h, wft, bfin, out, (t >> 5) * 128, (t & 31) * 128,
                       As, Bs, wave, lane);
    }
}

// ======================= fallback kernels (R2 pipeline) =====================
__global__ void activity_kernel(const float* __restrict__ x, float* __restrict__ part) {
    const int chunk = blockIdx.y;
    const int tid = threadIdx.x;
    const int colf4 = tid & 127;
    const int rsub = tid >> 7;
    const float4* base = (const float4*)x + (size_t)chunk * 128 + colf4;
    float s = 0.f;
    #pragma unroll 4
    for (int i = 0; i < 32; ++i) {
        int row = blockIdx.x * 64 + i * 2 + rsub;
        float4 v = base[(size_t)row * 1024];
        s += fabsf(v.x) + fabsf(v.y) + fabsf(v.z) + fabsf(v.w);
    }
    #pragma unroll
    for (int off = 32; off > 0; off >>= 1) s += __shfl_down(s, off, 64);
    __shared__ float wsum[4];
    if ((tid & 63) == 0) wsum[tid >> 6] = s;
    __syncthreads();
    if (tid == 0) part[chunk * 64 + blockIdx.x] = wsum[0] + wsum[1] + wsum[2] + wsum[3];
}

__global__ void topk_kernel(const float* __restrict__ part, int* __restrict__ idx) {
    __shared__ float act[8];
    const int lane = threadIdx.x & 63;
    const int wave = threadIdx.x >> 6;
    float s = part[wave * 64 + lane];
    #pragma unroll
    for (int off = 32; off > 0; off >>= 1) s += __shfl_down(s, off, 64);
    if (lane == 0) act[wave] = s;
    __syncthreads();
    if (threadIdx.x == 0) {
        float v0 = -1e30f, v1 = -1e30f; int b0 = 0, b1 = 0;
        for (int i = 0; i < 8; ++i) {
            float v = act[i];
            if (v > v0) { v1 = v0; b1 = b0; v0 = v; b0 = i; }
            else if (v > v1) { v1 = v; b1 = i; }
        }
        idx[0] = b0; idx[1] = b1;
    }
}

__global__ void transpose_cvt_kernel(const float* __restrict__ src, unsigned short* __restrict__ dst,
                                     int R, int C, const int* __restrict__ idx, int chunk_elems) {
    if (idx) { src += (size_t)idx[blockIdx.z] * chunk_elems; dst += (size_t)blockIdx.z * chunk_elems; }
    __shared__ float tile[32][33];
    const int tx = threadIdx.x, ty = threadIdx.y;
    const int cb = blockIdx.x * 32, rb = blockIdx.y * 32;
    #pragma unroll
    for (int i = 0; i < 4; ++i)
        tile[ty + i * 8][tx] = src[(size_t)(rb + ty + i * 8) * C + cb + tx];
    __syncthreads();
    #pragma unroll
    for (int i = 0; i < 4; ++i)
        dst[(size_t)(cb + ty + i * 8) * R + rb + tx] = f2bf(tile[tx][ty + i * 8]);
}

__global__ __launch_bounds__(256, 2)
void gemm1_kernel(const float* __restrict__ x, const unsigned short* __restrict__ wct,
                  const float* __restrict__ bc, const int* __restrict__ idx,
                  unsigned short* __restrict__ h) {
    __shared__ __align__(16) unsigned short As[64 * 64];
    __shared__ __align__(16) unsigned short Bs[64 * 64];
    const int z = blockIdx.z;
    gemm1_tile(x, wct, bc, h, z, idx[z], blockIdx.x * 64, blockIdx.y * 64,
               As, Bs, threadIdx.x, threadIdx.x >> 6, threadIdx.x & 63);
}

__global__ __launch_bounds__(256, 2)
void gemm2_kernel(const unsigned short* __restrict__ h, const unsigned short* __restrict__ wft,
                  const float* __restrict__ bfin, float* __restrict__ out) {
    __shared__ __align__(16) unsigned short As[128 * 64];
    __shared__ __align__(16) unsigned short Bs[128 * 64];
    gemm2_tile(h, wft, bfin, out, blockIdx.x * 128, blockIdx.y * 128,
               As, Bs, threadIdx.x >> 6, threadIdx.x & 63);
}

// ---------------------------------------------------------------------------
extern "C" void kernel_launch(void* const* d_in, const int* in_sizes, int n_in,
                              void* d_out, int out_size, void* d_ws, size_t ws_size,
                              hipStream_t stream) {
    const float* x    = (const float*)d_in[0];   // (4096, 4096)
    const float* Wc   = (const float*)d_in[1];   // (8, 512, 512)
    const float* bc   = (const float*)d_in[2];   // (8, 512)
    const float* Wf   = (const float*)d_in[3];   // (1024, 4096)
    const float* bfin = (const float*)d_in[4];   // (4096,)
    float* out = (float*)d_out;                  // (4096, 4096) fp32

    float* part = (float*)d_ws;                                   // 512 f32
    int*   idxg = (int*)((char*)d_ws + 4096);                     // 2 int
    unsigned short* h   = (unsigned short*)((char*)d_ws + 8192);  // 4096x1024 bf16
    unsigned short* wct = h   + (size_t)4096 * 1024;              // 2x512x512 bf16
    unsigned short* wft = wct + (size_t)2 * 512 * 512;            // 4096x1024 bf16

    void* args[] = { (void*)&x, (void*)&Wc, (void*)&bc, (void*)&Wf, (void*)&bfin,
                     (void*)&out, (void*)&part, (void*)&idxg, (void*)&h,
                     (void*)&wct, (void*)&wft };
    hipError_t e = hipLaunchCooperativeKernel((const void*)mega_kernel, dim3(512),
                                              dim3(256), args, 0, stream);
    if (e != hipSuccess) {
        // deterministic fallback: R2 multi-kernel pipeline (same work each call)
        activity_kernel<<<dim3(64, 8), 256, 0, stream>>>(x, part);
        topk_kernel<<<1, 512, 0, stream>>>(part, idxg);
        transpose_cvt_kernel<<<dim3(16, 16, 2), dim3(32, 8), 0, stream>>>(Wc, wct, 512, 512, idxg, 512 * 512);
        transpose_cvt_kernel<<<dim3(128, 32, 1), dim3(32, 8), 0, stream>>>(Wf, wft, 1024, 4096, nullptr, 0);
        gemm1_kernel<<<dim3(64, 8, 2), 256, 0, stream>>>(x, wct, bc, idxg, h);
        gemm2_kernel<<<dim3(32, 32, 1), 256, 0, stream>>>(h, wft, bfin, out);
    }
}

// Round 5
// 215.690 us; speedup vs baseline: 2.9813x; 2.9813x over previous
//
#include <hip/hip_runtime.h>

// ---------------------------------------------------------------------------
// R5 pipeline (4 kernels + 1 tiny memset; cooperative path abandoned —
// grid.sync measured ~100us each on this stack):
//   K1 activity_topk: per-chunk |x| sums via atomicAdd + last-block ticket
//                     computes top-2 -> idxg
//   K2 prep (job-indexed): gather x_sel -> bf16 (4096 jobs),
//                     Wf^T -> bf16 (4096 jobs), Wc[idx]^T -> bf16 (512 jobs)
//   K3 gemm1: h = xsel @ Wc + bc   (64x128 tile, all-async glds staging)
//   K4 gemm2: out = h @ Wf + b_final (128x128 tile, glds, 3 blocks/CU)
// ---------------------------------------------------------------------------

typedef __bf16 bf16x8_t __attribute__((ext_vector_type(8)));
typedef float  f32x4_t  __attribute__((ext_vector_type(4)));

__device__ inline unsigned short f2bf(float f) {
    __bf16 b = (__bf16)f;
    return __builtin_bit_cast(unsigned short, b);
}

// async stage of 8 rows (wave-uniform row0) from bf16 global, 16 B/lane,
// XOR-swizzled granules: LDS slot gs holds global granule gs ^ (row & 7)
__device__ inline void stage_glds(const unsigned short* gtile, int stride, int row0,
                                  unsigned short* lds, int lane) {
    const int r8 = lane >> 3;
    const int gg = (lane & 7) ^ r8;
    const unsigned short* gp = gtile + (size_t)(row0 + r8) * stride + gg * 8;
    unsigned short* lp = lds + row0 * 64;
    __builtin_amdgcn_global_load_lds((const __attribute__((address_space(1))) void*)gp,
                                     (__attribute__((address_space(3))) void*)lp,
                                     16, 0, 0);
}

__device__ inline bf16x8_t ldsfrag(const unsigned short* Ls, int row, int kb) {
    return *(const bf16x8_t*)(Ls + row * 64 + (((kb >> 3) ^ (row & 7)) * 8));
}

// ---------------- K1: activity + top-2 (single launch) ---------------------
__global__ void activity_topk_kernel(const float* __restrict__ x, float* __restrict__ act,
                                     int* __restrict__ counter, int* __restrict__ idxg) {
    const int b = blockIdx.x;              // 512 blocks
    const int chunk = b & 7;
    const int rg = b >> 3;                 // 64 rows each
    const int tid = threadIdx.x;
    const int colf4 = tid & 127;
    const int rsub = tid >> 7;
    const float4* base = (const float4*)x + (size_t)chunk * 128 + colf4;
    float s = 0.f;
    #pragma unroll 4
    for (int i = 0; i < 32; ++i) {
        int row = rg * 64 + i * 2 + rsub;
        float4 v = base[(size_t)row * 1024];
        s += fabsf(v.x) + fabsf(v.y) + fabsf(v.z) + fabsf(v.w);
    }
    #pragma unroll
    for (int off = 32; off > 0; off >>= 1) s += __shfl_down(s, off, 64);
    __shared__ float wsum[4];
    if ((tid & 63) == 0) wsum[tid >> 6] = s;
    __syncthreads();
    if (tid == 0) {
        atomicAdd(&act[chunk], wsum[0] + wsum[1] + wsum[2] + wsum[3]);
        __threadfence();
        int old = atomicAdd(counter, 1);
        if (old == gridDim.x - 1) {        // last block: routing decision
            float v0 = -1e30f, v1 = -1e30f; int b0 = 0, b1 = 0;
            for (int i = 0; i < 8; ++i) {
                float v = atomicAdd(&act[i], 0.0f);   // device-scope read
                if (v > v0) { v1 = v0; b1 = b0; v0 = v; b0 = i; }
                else if (v > v1) { v1 = v; b1 = i; }
            }
            idxg[0] = b0; idxg[1] = b1;
            __threadfence();
        }
    }
}

// ---------------- K2: prep — gather + transposes (job-indexed) -------------
__global__ void prep_kernel(const float* __restrict__ x, const float* __restrict__ Wc,
                            const float* __restrict__ Wf, const int* __restrict__ idxg,
                            unsigned short* __restrict__ xsel, unsigned short* __restrict__ wct,
                            unsigned short* __restrict__ wft) {
    const int j = blockIdx.x;              // 8704 jobs
    const int tid = threadIdx.x;
    if (j < 4096) {
        // gather row j of x_sel (1024 bf16): cols z*512.. from chunk idxg[z]
        const int c = tid * 4;
        const int z = c >> 9;
        const int sc = idxg[z] * 512 + (c & 511);
        float4 v = *(const float4*)(x + (size_t)j * 4096 + sc);
        ushort4 o;
        o.x = f2bf(v.x); o.y = f2bf(v.y); o.z = f2bf(v.z); o.w = f2bf(v.w);
        *(ushort4*)(xsel + (size_t)j * 1024 + c) = o;
        return;
    }
    __shared__ float tile[32][33];
    const int tx = tid & 31, ty = tid >> 5;
    const float* src; unsigned short* dst; int R, C, cb, rb;
    if (j < 8192) {                        // Wf^T: (1024,4096) -> (4096,1024)
        int jj = j - 4096;
        src = Wf; dst = wft; R = 1024; C = 4096;
        cb = (jj & 127) * 32; rb = (jj >> 7) * 32;
    } else {                               // Wc[idx[z]]^T: (512,512) -> (512,512)
        int jj = j - 8192;
        int z = jj >> 8, t = jj & 255;
        src = Wc + (size_t)idxg[z] * 262144;
        dst = wct + (size_t)z * 262144;
        R = 512; C = 512;
        cb = (t & 15) * 32; rb = (t >> 4) * 32;
    }
    #pragma unroll
    for (int i = 0; i < 4; ++i)
        tile[ty + i * 8][tx] = src[(size_t)(rb + ty + i * 8) * C + cb + tx];
    __syncthreads();
    #pragma unroll
    for (int i = 0; i < 4; ++i)
        dst[(size_t)(cb + ty + i * 8) * R + rb + tx] = f2bf(tile[tx][ty + i * 8]);
}

// ---------------- K3: GEMM1 — 64x128 tile, all-async staging ---------------
// h[m][z*512+n] = sum_k xsel[m][z*512+k] * wct[z][n][k] + bc[idx[z]][n]
__global__ __launch_bounds__(256, 4)
void gemm1_kernel(const unsigned short* __restrict__ xsel, const unsigned short* __restrict__ wct,
                  const float* __restrict__ bc, const int* __restrict__ idxg,
                  unsigned short* __restrict__ h) {
    __shared__ __align__(16) unsigned short As[64 * 64];    // 8 KB
    __shared__ __align__(16) unsigned short Bs[128 * 64];   // 16 KB
    const int z = blockIdx.z;
    const int idxz = idxg[z];
    const int m0 = blockIdx.x * 64;
    const int n0 = blockIdx.y * 128;
    const int tid = threadIdx.x;
    const int wave = tid >> 6;
    const int lane = tid & 63;
    const int wm = (wave >> 1) * 32;
    const int wn = (wave & 1) * 64;
    const int rl = lane & 15;
    const int quad = lane >> 4;

    const unsigned short* Atile = xsel + (size_t)m0 * 1024 + z * 512;
    const unsigned short* Btile = wct + (size_t)z * 262144 + (size_t)n0 * 512;

    f32x4_t acc[2][4] = {};

    for (int k0 = 0; k0 < 512; k0 += 64) {
        #pragma unroll
        for (int s = wave; s < 24; s += 4) {
            if (s < 8) stage_glds(Atile + k0, 1024, s * 8, As, lane);
            else       stage_glds(Btile + k0, 512, (s - 8) * 8, Bs, lane);
        }
        __syncthreads();
        #pragma unroll
        for (int kq = 0; kq < 2; ++kq) {
            const int kb = kq * 32 + quad * 8;
            bf16x8_t af[2], bfr[4];
            #pragma unroll
            for (int i = 0; i < 2; ++i) af[i]  = ldsfrag(As, wm + i * 16 + rl, kb);
            #pragma unroll
            for (int i = 0; i < 4; ++i) bfr[i] = ldsfrag(Bs, wn + i * 16 + rl, kb);
            #pragma unroll
            for (int mi = 0; mi < 2; ++mi)
                #pragma unroll
                for (int ni = 0; ni < 4; ++ni)
                    acc[mi][ni] = __builtin_amdgcn_mfma_f32_16x16x32_bf16(af[mi], bfr[ni], acc[mi][ni], 0, 0, 0);
        }
        __syncthreads();
    }

    const int row_l = quad * 4;
    const float* bias = bc + (size_t)idxz * 512;
    #pragma unroll
    for (int ni = 0; ni < 4; ++ni) {
        int col = n0 + wn + ni * 16 + rl;       // within this z's 512
        float bv = bias[col];
        #pragma unroll
        for (int mi = 0; mi < 2; ++mi) {
            #pragma unroll
            for (int j = 0; j < 4; ++j) {
                int row = m0 + wm + mi * 16 + row_l + j;
                h[(size_t)row * 1024 + z * 512 + col] = f2bf(acc[mi][ni][j] + bv);
            }
        }
    }
}

// ---------------- K4: GEMM2 — 128x128 tile, 3 blocks/CU --------------------
__global__ __launch_bounds__(256, 3)
void gemm2_kernel(const unsigned short* __restrict__ h, const unsigned short* __restrict__ wft,
                  const float* __restrict__ bfin, float* __restrict__ out) {
    __shared__ __align__(16) unsigned short As[128 * 64];   // 16 KB
    __shared__ __align__(16) unsigned short Bs[128 * 64];   // 16 KB
    const int m0 = blockIdx.x * 128;
    const int n0 = blockIdx.y * 128;
    const int tid = threadIdx.x;
    const int wave = tid >> 6;
    const int lane = tid & 63;
    const int wm = (wave >> 1) * 64;
    const int wn = (wave & 1) * 64;
    const int rl = lane & 15;
    const int quad = lane >> 4;

    const unsigned short* Atile = h + (size_t)m0 * 1024;
    const unsigned short* Btile = wft + (size_t)n0 * 1024;

    f32x4_t acc[4][4] = {};

    for (int k0 = 0; k0 < 1024; k0 += 64) {
        #pragma unroll
        for (int s = wave; s < 32; s += 4) {
            if (s < 16) stage_glds(Atile + k0, 1024, s * 8, As, lane);
            else        stage_glds(Btile + k0, 1024, (s - 16) * 8, Bs, lane);
        }
        __syncthreads();
        #pragma unroll
        for (int kq = 0; kq < 2; ++kq) {
            const int kb = kq * 32 + quad * 8;
            bf16x8_t af[4], bfr[4];
            #pragma unroll
            for (int i = 0; i < 4; ++i) {
                af[i]  = ldsfrag(As, wm + i * 16 + rl, kb);
                bfr[i] = ldsfrag(Bs, wn + i * 16 + rl, kb);
            }
            #pragma unroll
            for (int mi = 0; mi < 4; ++mi)
                #pragma unroll
                for (int ni = 0; ni < 4; ++ni)
                    acc[mi][ni] = __builtin_amdgcn_mfma_f32_16x16x32_bf16(af[mi], bfr[ni], acc[mi][ni], 0, 0, 0);
        }
        __syncthreads();
    }

    const int row_l = quad * 4;
    float bv[4];
    #pragma unroll
    for (int ni = 0; ni < 4; ++ni) bv[ni] = bfin[n0 + wn + ni * 16 + rl];
    #pragma unroll
    for (int mi = 0; mi < 4; ++mi) {
        #pragma unroll
        for (int ni = 0; ni < 4; ++ni) {
            int col = n0 + wn + ni * 16 + rl;
            #pragma unroll
            for (int j = 0; j < 4; ++j) {
                int row = m0 + wm + mi * 16 + row_l + j;
                out[(size_t)row * 4096 + col] = acc[mi][ni][j] + bv[ni];
            }
        }
    }
}

// ---------------------------------------------------------------------------
extern "C" void kernel_launch(void* const* d_in, const int* in_sizes, int n_in,
                              void* d_out, int out_size, void* d_ws, size_t ws_size,
                              hipStream_t stream) {
    const float* x    = (const float*)d_in[0];   // (4096, 4096)
    const float* Wc   = (const float*)d_in[1];   // (8, 512, 512)
    const float* bc   = (const float*)d_in[2];   // (8, 512)
    const float* Wf   = (const float*)d_in[3];   // (1024, 4096)
    const float* bfin = (const float*)d_in[4];   // (4096,)
    float* out = (float*)d_out;                  // (4096, 4096) fp32

    // workspace (~26.2 MB)
    float* act     = (float*)d_ws;                                // 8 f32
    int*   counter = (int*)((char*)d_ws + 64);                    // 1 int
    int*   idxg    = (int*)((char*)d_ws + 128);                   // 2 int
    unsigned short* xsel = (unsigned short*)((char*)d_ws + 4096); // 4096x1024 bf16
    unsigned short* h    = xsel + (size_t)4096 * 1024;            // 4096x1024 bf16
    unsigned short* wct  = h    + (size_t)4096 * 1024;            // 2x512x512 bf16
    unsigned short* wft  = wct  + (size_t)2 * 512 * 512;          // 4096x1024 bf16

    hipMemsetAsync(d_ws, 0, 128, stream);  // zero act + counter

    activity_topk_kernel<<<512, 256, 0, stream>>>(x, act, counter, idxg);
    prep_kernel<<<8704, 256, 0, stream>>>(x, Wc, Wf, idxg, xsel, wct, wft);
    gemm1_kernel<<<dim3(64, 4, 2), 256, 0, stream>>>(xsel, wct, bc, idxg, h);
    gemm2_kernel<<<dim3(32, 32, 1), 256, 0, stream>>>(h, wft, bfin, out);
}

// Round 6
// 185.342 us; speedup vs baseline: 3.4694x; 1.1637x over previous
//
#include <hip/hip_runtime.h>

// ---------------------------------------------------------------------------
// R6: 3-node pipeline, no sync primitives, no memset:
//   K1 fused_prep (6656 blocks, job-typed — all jobs independent):
//       b <  512  : activity partials part[c*64+rg] = sum |x[rows, chunk c]|
//       b < 4608  : Wf^T tile -> wft (4096x1024 bf16)
//       else      : Wc[c]^T tile -> wct, ALL 8 chunks (removes idx dependency)
//   K2 gemm1 (64x128 tile): prologue reduces part[512] -> top-2 (redundant
//       per block, ~8 scalar ops); A = x[:, idx[z]] fp32->bf16 fused gather,
//       B = wct[idx[z]] via global_load_lds; h = A@B + bc[idx[z]]
//   K3 gemm2 (128x128 tile, glds + XOR swizzle): out = h @ Wf^T + b_final
// ---------------------------------------------------------------------------

typedef __bf16 bf16x8_t __attribute__((ext_vector_type(8)));
typedef float  f32x4_t  __attribute__((ext_vector_type(4)));

__device__ inline unsigned short f2bf(float f) {
    __bf16 b = (__bf16)f;
    return __builtin_bit_cast(unsigned short, b);
}

// async stage of 8 rows (wave-uniform row0) from bf16 global, 16 B/lane,
// XOR-swizzled granules: LDS slot gs holds global granule gs ^ (row & 7)
__device__ inline void stage_glds(const unsigned short* gtile, int stride, int row0,
                                  unsigned short* lds, int lane) {
    const int r8 = lane >> 3;
    const int gg = (lane & 7) ^ r8;
    const unsigned short* gp = gtile + (size_t)(row0 + r8) * stride + gg * 8;
    unsigned short* lp = lds + row0 * 64;
    __builtin_amdgcn_global_load_lds((const __attribute__((address_space(1))) void*)gp,
                                     (__attribute__((address_space(3))) void*)lp,
                                     16, 0, 0);
}

__device__ inline bf16x8_t ldsfrag(const unsigned short* Ls, int row, int kb) {
    return *(const bf16x8_t*)(Ls + row * 64 + (((kb >> 3) ^ (row & 7)) * 8));
}

// ---------------- K1: fused activity-partials + all transposes -------------
__global__ void fused_prep_kernel(const float* __restrict__ x, const float* __restrict__ Wc,
                                  const float* __restrict__ Wf, float* __restrict__ part,
                                  unsigned short* __restrict__ wct, unsigned short* __restrict__ wft) {
    const int b = blockIdx.x;
    const int tid = threadIdx.x;

    if (b < 512) {
        // activity partial: chunk = b&7, row-group rg = b>>3 (64 rows)
        const int chunk = b & 7;
        const int rg = b >> 3;
        const int colf4 = tid & 127;
        const int rsub = tid >> 7;
        const float4* base = (const float4*)x + (size_t)chunk * 128 + colf4;
        float s = 0.f;
        #pragma unroll 4
        for (int i = 0; i < 32; ++i) {
            int row = rg * 64 + i * 2 + rsub;
            float4 v = base[(size_t)row * 1024];
            s += fabsf(v.x) + fabsf(v.y) + fabsf(v.z) + fabsf(v.w);
        }
        #pragma unroll
        for (int off = 32; off > 0; off >>= 1) s += __shfl_down(s, off, 64);
        __shared__ float wsum[4];
        if ((tid & 63) == 0) wsum[tid >> 6] = s;
        __syncthreads();
        if (tid == 0) part[chunk * 64 + rg] = wsum[0] + wsum[1] + wsum[2] + wsum[3];
        return;
    }

    // transpose jobs
    __shared__ float tile[32][33];
    const int tx = tid & 31, ty = tid >> 5;
    const float* src; unsigned short* dst; int R, C, cb, rb;
    int jj = b - 512;
    if (jj < 4096) {                       // Wf^T: (1024,4096) -> (4096,1024)
        src = Wf; dst = wft; R = 1024; C = 4096;
        cb = (jj & 127) * 32; rb = (jj >> 7) * 32;
    } else {                               // Wc[c]^T for ALL c: (512,512)->(512,512)
        jj -= 4096;
        int c = jj >> 8, t = jj & 255;
        src = Wc + (size_t)c * 262144;
        dst = wct + (size_t)c * 262144;
        R = 512; C = 512;
        cb = (t & 15) * 32; rb = (t >> 4) * 32;
    }
    #pragma unroll
    for (int i = 0; i < 4; ++i)
        tile[ty + i * 8][tx] = src[(size_t)(rb + ty + i * 8) * C + cb + tx];
    __syncthreads();
    #pragma unroll
    for (int i = 0; i < 4; ++i)
        dst[(size_t)(cb + ty + i * 8) * R + rb + tx] = f2bf(tile[tx][ty + i * 8]);
}

// ---------------- K2: GEMM1 — topk prologue + fused gather -----------------
// h[m][z*512+n] = sum_k x[m][idx[z]*512+k] * Wc[idx[z]][k][n] + bc[idx[z]][n]
__global__ __launch_bounds__(256, 2)
void gemm1_kernel(const float* __restrict__ x, const unsigned short* __restrict__ wct,
                  const float* __restrict__ bc, const float* __restrict__ part,
                  unsigned short* __restrict__ h) {
    __shared__ __align__(16) unsigned char lds_raw[24576];
    unsigned short* As = (unsigned short*)lds_raw;            // 8 KB (64x64)
    unsigned short* Bs = (unsigned short*)(lds_raw + 8192);   // 16 KB (128x64)

    const int tid = threadIdx.x;
    const int wave = tid >> 6;
    const int lane = tid & 63;

    // --- prologue: reduce part[512] -> act[8] -> top-2 (redundant/block) ---
    {
        float* sred = (float*)lds_raw;         // 512 floats
        sred[tid] = part[tid];
        sred[tid + 256] = part[tid + 256];
        __syncthreads();
        float* act8 = (float*)(lds_raw + 2048);
        if (tid < 8) {
            float a = 0.f;
            #pragma unroll
            for (int k = 0; k < 64; ++k) a += sred[tid * 64 + k];
            act8[tid] = a;
        }
        __syncthreads();
    }
    int sel0, sel1;
    {
        const float* act8 = (const float*)(lds_raw + 2048);
        float v0 = -1e30f, v1 = -1e30f; int b0 = 0, b1 = 0;
        #pragma unroll
        for (int i = 0; i < 8; ++i) {
            float v = act8[i];
            if (v > v0) { v1 = v0; b1 = b0; v0 = v; b0 = i; }
            else if (v > v1) { v1 = v; b1 = i; }
        }
        sel0 = b0; sel1 = b1;
    }
    __syncthreads();   // done reading act8 before LDS reuse as As/Bs

    const int z = blockIdx.z;
    const int idxz = z ? sel1 : sel0;
    const int m0 = blockIdx.x * 64;
    const int n0 = blockIdx.y * 128;
    const int wm = (wave >> 1) * 32;
    const int wn = (wave & 1) * 64;
    const int rl = lane & 15;
    const int quad = lane >> 4;

    const float* xtile = x + (size_t)m0 * 4096 + idxz * 512;
    const unsigned short* Btile = wct + (size_t)idxz * 262144 + (size_t)n0 * 512;

    f32x4_t acc[2][4] = {};
    const int ar = tid >> 2;      // A staging row 0..63
    const int aq = tid & 3;       // granule pair

    for (int k0 = 0; k0 < 512; k0 += 64) {
        // B: async glds, 16 segments of 8 rows, 4 per wave
        #pragma unroll
        for (int s = wave; s < 16; s += 4)
            stage_glds(Btile + k0, 512, s * 8, Bs, lane);
        // A: fp32 -> bf16 via VGPRs (fused gather)
        const float* gr = xtile + (size_t)ar * 4096 + k0;
        #pragma unroll
        for (int j = 0; j < 2; ++j) {
            int gg = aq * 2 + j;
            float4 a = *(const float4*)(gr + gg * 8);
            float4 c = *(const float4*)(gr + gg * 8 + 4);
            bf16x8_t v;
            v[0] = (__bf16)a.x; v[1] = (__bf16)a.y; v[2] = (__bf16)a.z; v[3] = (__bf16)a.w;
            v[4] = (__bf16)c.x; v[5] = (__bf16)c.y; v[6] = (__bf16)c.z; v[7] = (__bf16)c.w;
            *(bf16x8_t*)(As + ar * 64 + ((gg ^ (ar & 7)) * 8)) = v;
        }
        __syncthreads();
        #pragma unroll
        for (int kq = 0; kq < 2; ++kq) {
            const int kb = kq * 32 + quad * 8;
            bf16x8_t af[2], bfr[4];
            #pragma unroll
            for (int i = 0; i < 2; ++i) af[i]  = ldsfrag(As, wm + i * 16 + rl, kb);
            #pragma unroll
            for (int i = 0; i < 4; ++i) bfr[i] = ldsfrag(Bs, wn + i * 16 + rl, kb);
            #pragma unroll
            for (int mi = 0; mi < 2; ++mi)
                #pragma unroll
                for (int ni = 0; ni < 4; ++ni)
                    acc[mi][ni] = __builtin_amdgcn_mfma_f32_16x16x32_bf16(af[mi], bfr[ni], acc[mi][ni], 0, 0, 0);
        }
        __syncthreads();
    }

    const int row_l = quad * 4;
    const float* bias = bc + (size_t)idxz * 512;
    #pragma unroll
    for (int ni = 0; ni < 4; ++ni) {
        int col = n0 + wn + ni * 16 + rl;
        float bv = bias[col];
        #pragma unroll
        for (int mi = 0; mi < 2; ++mi) {
            #pragma unroll
            for (int j = 0; j < 4; ++j) {
                int row = m0 + wm + mi * 16 + row_l + j;
                h[(size_t)row * 1024 + z * 512 + col] = f2bf(acc[mi][ni][j] + bv);
            }
        }
    }
}

// ---------------- K3: GEMM2 — 128x128 tile (unchanged structure) -----------
__global__ __launch_bounds__(256, 3)
void gemm2_kernel(const unsigned short* __restrict__ h, const unsigned short* __restrict__ wft,
                  const float* __restrict__ bfin, float* __restrict__ out) {
    __shared__ __align__(16) unsigned short As[128 * 64];   // 16 KB
    __shared__ __align__(16) unsigned short Bs[128 * 64];   // 16 KB
    const int m0 = blockIdx.x * 128;
    const int n0 = blockIdx.y * 128;
    const int tid = threadIdx.x;
    const int wave = tid >> 6;
    const int lane = tid & 63;
    const int wm = (wave >> 1) * 64;
    const int wn = (wave & 1) * 64;
    const int rl = lane & 15;
    const int quad = lane >> 4;

    const unsigned short* Atile = h + (size_t)m0 * 1024;
    const unsigned short* Btile = wft + (size_t)n0 * 1024;

    f32x4_t acc[4][4] = {};

    for (int k0 = 0; k0 < 1024; k0 += 64) {
        #pragma unroll
        for (int s = wave; s < 32; s += 4) {
            if (s < 16) stage_glds(Atile + k0, 1024, s * 8, As, lane);
            else        stage_glds(Btile + k0, 1024, (s - 16) * 8, Bs, lane);
        }
        __syncthreads();
        #pragma unroll
        for (int kq = 0; kq < 2; ++kq) {
            const int kb = kq * 32 + quad * 8;
            bf16x8_t af[4], bfr[4];
            #pragma unroll
            for (int i = 0; i < 4; ++i) {
                af[i]  = ldsfrag(As, wm + i * 16 + rl, kb);
                bfr[i] = ldsfrag(Bs, wn + i * 16 + rl, kb);
            }
            #pragma unroll
            for (int mi = 0; mi < 4; ++mi)
                #pragma unroll
                for (int ni = 0; ni < 4; ++ni)
                    acc[mi][ni] = __builtin_amdgcn_mfma_f32_16x16x32_bf16(af[mi], bfr[ni], acc[mi][ni], 0, 0, 0);
        }
        __syncthreads();
    }

    const int row_l = quad * 4;
    float bv[4];
    #pragma unroll
    for (int ni = 0; ni < 4; ++ni) bv[ni] = bfin[n0 + wn + ni * 16 + rl];
    #pragma unroll
    for (int mi = 0; mi < 4; ++mi) {
        #pragma unroll
        for (int ni = 0; ni < 4; ++ni) {
            int col = n0 + wn + ni * 16 + rl;
            #pragma unroll
            for (int j = 0; j < 4; ++j) {
                int row = m0 + wm + mi * 16 + row_l + j;
                out[(size_t)row * 4096 + col] = acc[mi][ni][j] + bv[ni];
            }
        }
    }
}

// ---------------------------------------------------------------------------
extern "C" void kernel_launch(void* const* d_in, const int* in_sizes, int n_in,
                              void* d_out, int out_size, void* d_ws, size_t ws_size,
                              hipStream_t stream) {
    const float* x    = (const float*)d_in[0];   // (4096, 4096)
    const float* Wc   = (const float*)d_in[1];   // (8, 512, 512)
    const float* bc   = (const float*)d_in[2];   // (8, 512)
    const float* Wf   = (const float*)d_in[3];   // (1024, 4096)
    const float* bfin = (const float*)d_in[4];   // (4096,)
    float* out = (float*)d_out;                  // (4096, 4096) fp32

    // workspace (~21 MB): part fully rewritten each call (no zeroing needed)
    float* part = (float*)d_ws;                                    // 512 f32
    unsigned short* h   = (unsigned short*)((char*)d_ws + 4096);   // 4096x1024 bf16
    unsigned short* wct = h   + (size_t)4096 * 1024;               // 8x512x512 bf16 (all chunks ^T)
    unsigned short* wft = wct + (size_t)8 * 512 * 512;             // 4096x1024 bf16 (Wf^T)

    // 512 activity + 4096 Wf^T + 2048 Wc^T jobs
    fused_prep_kernel<<<6656, 256, 0, stream>>>(x, Wc, Wf, part, wct, wft);
    gemm1_kernel<<<dim3(64, 4, 2), 256, 0, stream>>>(x, wct, bc, part, h);
    gemm2_kernel<<<dim3(32, 32, 1), 256, 0, stream>>>(h, wft, bfin, out);
}

// Round 7
// 181.311 us; speedup vs baseline: 3.5466x; 1.0222x over previous
//
#include <hip/hip_runtime.h>

// ---------------------------------------------------------------------------
// R7: same 3-node pipeline as R6; gemm kernels pinned under the 128-reg
// occupancy cliff (__launch_bounds__(256,4): 4 waves/SIMD -> 4 blocks/CU;
// R2's fastest gemm2 (49us) was the VGPR=64 build, R6's 57.6us was VGPR=68).
//   K1 fused_prep (6656 blocks): activity partials + Wf^T + all-8 Wc^T
//   K2 gemm1 (64x128): per-block topk prologue + fused fp32 gather
//   K3 gemm2 (128x128): glds staging + XOR swizzle, j-outer epilogue
// ---------------------------------------------------------------------------

typedef __bf16 bf16x8_t __attribute__((ext_vector_type(8)));
typedef float  f32x4_t  __attribute__((ext_vector_type(4)));

__device__ inline unsigned short f2bf(float f) {
    __bf16 b = (__bf16)f;
    return __builtin_bit_cast(unsigned short, b);
}

// async stage of 8 rows (wave-uniform row0) from bf16 global, 16 B/lane,
// XOR-swizzled granules: LDS slot gs holds global granule gs ^ (row & 7)
__device__ inline void stage_glds(const unsigned short* gtile, int stride, int row0,
                                  unsigned short* lds, int lane) {
    const int r8 = lane >> 3;
    const int gg = (lane & 7) ^ r8;
    const unsigned short* gp = gtile + (size_t)(row0 + r8) * stride + gg * 8;
    unsigned short* lp = lds + row0 * 64;
    __builtin_amdgcn_global_load_lds((const __attribute__((address_space(1))) void*)gp,
                                     (__attribute__((address_space(3))) void*)lp,
                                     16, 0, 0);
}

__device__ inline bf16x8_t ldsfrag(const unsigned short* Ls, int row, int kb) {
    return *(const bf16x8_t*)(Ls + row * 64 + (((kb >> 3) ^ (row & 7)) * 8));
}

// ---------------- K1: fused activity-partials + all transposes -------------
__global__ void fused_prep_kernel(const float* __restrict__ x, const float* __restrict__ Wc,
                                  const float* __restrict__ Wf, float* __restrict__ part,
                                  unsigned short* __restrict__ wct, unsigned short* __restrict__ wft) {
    const int b = blockIdx.x;
    const int tid = threadIdx.x;

    if (b < 512) {
        const int chunk = b & 7;
        const int rg = b >> 3;
        const int colf4 = tid & 127;
        const int rsub = tid >> 7;
        const float4* base = (const float4*)x + (size_t)chunk * 128 + colf4;
        float s = 0.f;
        #pragma unroll 4
        for (int i = 0; i < 32; ++i) {
            int row = rg * 64 + i * 2 + rsub;
            float4 v = base[(size_t)row * 1024];
            s += fabsf(v.x) + fabsf(v.y) + fabsf(v.z) + fabsf(v.w);
        }
        #pragma unroll
        for (int off = 32; off > 0; off >>= 1) s += __shfl_down(s, off, 64);
        __shared__ float wsum[4];
        if ((tid & 63) == 0) wsum[tid >> 6] = s;
        __syncthreads();
        if (tid == 0) part[chunk * 64 + rg] = wsum[0] + wsum[1] + wsum[2] + wsum[3];
        return;
    }

    __shared__ float tile[32][33];
    const int tx = tid & 31, ty = tid >> 5;
    const float* src; unsigned short* dst; int R, C, cb, rb;
    int jj = b - 512;
    if (jj < 4096) {                       // Wf^T: (1024,4096) -> (4096,1024)
        src = Wf; dst = wft; R = 1024; C = 4096;
        cb = (jj & 127) * 32; rb = (jj >> 7) * 32;
    } else {                               // Wc[c]^T for ALL c
        jj -= 4096;
        int c = jj >> 8, t = jj & 255;
        src = Wc + (size_t)c * 262144;
        dst = wct + (size_t)c * 262144;
        R = 512; C = 512;
        cb = (t & 15) * 32; rb = (t >> 4) * 32;
    }
    #pragma unroll
    for (int i = 0; i < 4; ++i)
        tile[ty + i * 8][tx] = src[(size_t)(rb + ty + i * 8) * C + cb + tx];
    __syncthreads();
    #pragma unroll
    for (int i = 0; i < 4; ++i)
        dst[(size_t)(cb + ty + i * 8) * R + rb + tx] = f2bf(tile[tx][ty + i * 8]);
}

// ---------------- K2: GEMM1 — topk prologue + fused gather -----------------
__global__ __launch_bounds__(256, 4)
void gemm1_kernel(const float* __restrict__ x, const unsigned short* __restrict__ wct,
                  const float* __restrict__ bc, const float* __restrict__ part,
                  unsigned short* __restrict__ h) {
    __shared__ __align__(16) unsigned char lds_raw[24576];
    unsigned short* As = (unsigned short*)lds_raw;            // 8 KB (64x64)
    unsigned short* Bs = (unsigned short*)(lds_raw + 8192);   // 16 KB (128x64)

    const int tid = threadIdx.x;
    const int wave = tid >> 6;
    const int lane = tid & 63;

    // prologue: reduce part[512] -> act[8] -> top-2 (redundant per block)
    {
        float* sred = (float*)lds_raw;
        sred[tid] = part[tid];
        sred[tid + 256] = part[tid + 256];
        __syncthreads();
        float* act8 = (float*)(lds_raw + 2048);
        if (tid < 8) {
            float a = 0.f;
            #pragma unroll
            for (int k = 0; k < 64; ++k) a += sred[tid * 64 + k];
            act8[tid] = a;
        }
        __syncthreads();
    }
    int sel0, sel1;
    {
        const float* act8 = (const float*)(lds_raw + 2048);
        float v0 = -1e30f, v1 = -1e30f; int b0 = 0, b1 = 0;
        #pragma unroll
        for (int i = 0; i < 8; ++i) {
            float v = act8[i];
            if (v > v0) { v1 = v0; b1 = b0; v0 = v; b0 = i; }
            else if (v > v1) { v1 = v; b1 = i; }
        }
        sel0 = b0; sel1 = b1;
    }
    __syncthreads();

    const int z = blockIdx.z;
    const int idxz = z ? sel1 : sel0;
    const int m0 = blockIdx.x * 64;
    const int n0 = blockIdx.y * 128;
    const int wm = (wave >> 1) * 32;
    const int wn = (wave & 1) * 64;
    const int rl = lane & 15;
    const int quad = lane >> 4;

    const float* xtile = x + (size_t)m0 * 4096 + idxz * 512;
    const unsigned short* Btile = wct + (size_t)idxz * 262144 + (size_t)n0 * 512;

    f32x4_t acc[2][4] = {};
    const int ar = tid >> 2;
    const int aq = tid & 3;

    for (int k0 = 0; k0 < 512; k0 += 64) {
        #pragma unroll
        for (int s = wave; s < 16; s += 4)
            stage_glds(Btile + k0, 512, s * 8, Bs, lane);
        const float* gr = xtile + (size_t)ar * 4096 + k0;
        #pragma unroll
        for (int j = 0; j < 2; ++j) {
            int gg = aq * 2 + j;
            float4 a = *(const float4*)(gr + gg * 8);
            float4 c = *(const float4*)(gr + gg * 8 + 4);
            bf16x8_t v;
            v[0] = (__bf16)a.x; v[1] = (__bf16)a.y; v[2] = (__bf16)a.z; v[3] = (__bf16)a.w;
            v[4] = (__bf16)c.x; v[5] = (__bf16)c.y; v[6] = (__bf16)c.z; v[7] = (__bf16)c.w;
            *(bf16x8_t*)(As + ar * 64 + ((gg ^ (ar & 7)) * 8)) = v;
        }
        __syncthreads();
        #pragma unroll
        for (int kq = 0; kq < 2; ++kq) {
            const int kb = kq * 32 + quad * 8;
            bf16x8_t af[2], bfr[4];
            #pragma unroll
            for (int i = 0; i < 2; ++i) af[i]  = ldsfrag(As, wm + i * 16 + rl, kb);
            #pragma unroll
            for (int i = 0; i < 4; ++i) bfr[i] = ldsfrag(Bs, wn + i * 16 + rl, kb);
            #pragma unroll
            for (int mi = 0; mi < 2; ++mi)
                #pragma unroll
                for (int ni = 0; ni < 4; ++ni)
                    acc[mi][ni] = __builtin_amdgcn_mfma_f32_16x16x32_bf16(af[mi], bfr[ni], acc[mi][ni], 0, 0, 0);
        }
        __syncthreads();
    }

    const int row_l = quad * 4;
    const float* bias = bc + (size_t)idxz * 512;
    #pragma unroll
    for (int ni = 0; ni < 4; ++ni) {
        int col = n0 + wn + ni * 16 + rl;
        float bv = bias[col];
        #pragma unroll
        for (int mi = 0; mi < 2; ++mi) {
            #pragma unroll
            for (int j = 0; j < 4; ++j) {
                int row = m0 + wm + mi * 16 + row_l + j;
                h[(size_t)row * 1024 + z * 512 + col] = f2bf(acc[mi][ni][j] + bv);
            }
        }
    }
}

// ---------------- K3: GEMM2 — 128x128 tile, 4 blocks/CU target -------------
__global__ __launch_bounds__(256, 4)
void gemm2_kernel(const unsigned short* __restrict__ h, const unsigned short* __restrict__ wft,
                  const float* __restrict__ bfin, float* __restrict__ out) {
    __shared__ __align__(16) unsigned short As[128 * 64];   // 16 KB
    __shared__ __align__(16) unsigned short Bs[128 * 64];   // 16 KB
    const int m0 = blockIdx.x * 128;
    const int n0 = blockIdx.y * 128;
    const int tid = threadIdx.x;
    const int wave = tid >> 6;
    const int lane = tid & 63;
    const int wm = (wave >> 1) * 64;
    const int wn = (wave & 1) * 64;
    const int rl = lane & 15;
    const int quad = lane >> 4;

    const unsigned short* Atile = h + (size_t)m0 * 1024;
    const unsigned short* Btile = wft + (size_t)n0 * 1024;

    f32x4_t acc[4][4] = {};

    for (int k0 = 0; k0 < 1024; k0 += 64) {
        #pragma unroll
        for (int s = wave; s < 32; s += 4) {
            if (s < 16) stage_glds(Atile + k0, 1024, s * 8, As, lane);
            else        stage_glds(Btile + k0, 1024, (s - 16) * 8, Bs, lane);
        }
        __syncthreads();
        #pragma unroll
        for (int kq = 0; kq < 2; ++kq) {
            const int kb = kq * 32 + quad * 8;
            bf16x8_t af[4], bfr[4];
            #pragma unroll
            for (int i = 0; i < 4; ++i) {
                af[i]  = ldsfrag(As, wm + i * 16 + rl, kb);
                bfr[i] = ldsfrag(Bs, wn + i * 16 + rl, kb);
            }
            #pragma unroll
            for (int mi = 0; mi < 4; ++mi)
                #pragma unroll
                for (int ni = 0; ni < 4; ++ni)
                    acc[mi][ni] = __builtin_amdgcn_mfma_f32_16x16x32_bf16(af[mi], bfr[ni], acc[mi][ni], 0, 0, 0);
        }
        __syncthreads();
    }

    // epilogue: j-outer so consecutive stores walk within/near rows
    const int row_l = quad * 4;
    float bv[4];
    #pragma unroll
    for (int ni = 0; ni < 4; ++ni) bv[ni] = bfin[n0 + wn + ni * 16 + rl];
    #pragma unroll
    for (int j = 0; j < 4; ++j) {
        #pragma unroll
        for (int mi = 0; mi < 4; ++mi) {
            int row = m0 + wm + mi * 16 + row_l + j;
            float* orow = out + (size_t)row * 4096 + n0 + wn + rl;
            #pragma unroll
            for (int ni = 0; ni < 4; ++ni)
                orow[ni * 16] = acc[mi][ni][j] + bv[ni];
        }
    }
}

// ---------------------------------------------------------------------------
extern "C" void kernel_launch(void* const* d_in, const int* in_sizes, int n_in,
                              void* d_out, int out_size, void* d_ws, size_t ws_size,
                              hipStream_t stream) {
    const float* x    = (const float*)d_in[0];   // (4096, 4096)
    const float* Wc   = (const float*)d_in[1];   // (8, 512, 512)
    const float* bc   = (const float*)d_in[2];   // (8, 512)
    const float* Wf   = (const float*)d_in[3];   // (1024, 4096)
    const float* bfin = (const float*)d_in[4];   // (4096,)
    float* out = (float*)d_out;                  // (4096, 4096) fp32

    float* part = (float*)d_ws;                                    // 512 f32
    unsigned short* h   = (unsigned short*)((char*)d_ws + 4096);   // 4096x1024 bf16
    unsigned short* wct = h   + (size_t)4096 * 1024;               // 8x512x512 bf16
    unsigned short* wft = wct + (size_t)8 * 512 * 512;             // 4096x1024 bf16

    fused_prep_kernel<<<6656, 256, 0, stream>>>(x, Wc, Wf, part, wct, wft);
    gemm1_kernel<<<dim3(64, 4, 2), 256, 0, stream>>>(x, wct, bc, part, h);
    gemm2_kernel<<<dim3(32, 32, 1), 256, 0, stream>>>(h, wft, bfin, out);
}